// Round 17
// baseline (507.297 us; speedup 1.0000x reference)
//
#include <hip/hip_runtime.h>
#include <hip/hip_bf16.h>
#include <math.h>

#define NN 10000
#define NE 160000
#define NF 128
#define NB 20
#define CUT 5.0f
#define TPS 136   // u16 tile row stride
#define TPF 132   // fp32 tile row stride

typedef __attribute__((ext_vector_type(8))) short short8;
typedef __attribute__((ext_vector_type(4))) float floatx4;
typedef unsigned short u16;
typedef unsigned int u32;

__device__ __forceinline__ u16 f2b(float x){
  union { __hip_bfloat16 b; u16 u; } cv;
  cv.b = __float2bfloat16(x);
  return cv.u;
}
__device__ __forceinline__ float lo_bf(u32 w){ return __uint_as_float(w << 16); }
__device__ __forceinline__ float hi_bf(u32 w){ return __uint_as_float(w & 0xFFFF0000u); }
__device__ __forceinline__ float fast_silu(float v){
  return v * __builtin_amdgcn_rcpf(1.f + __expf(-v));
}
__device__ __forceinline__ float rdf(const void* p, size_t i, int isb){
  return isb ? __bfloat162float(((const __hip_bfloat16*)p)[i]) : ((const float*)p)[i];
}

// ---------------- dtype detector: 1=bf16, 0=fp32 ----------------
__global__ __launch_bounds__(256) void k_detect(const void* __restrict__ w, int nelem,
                                                int* __restrict__ flag){
  __shared__ int cnt;
  if (threadIdx.x == 0) cnt = 0;
  __syncthreads();
  const u16* hw = (const u16*)w;
  int local = 0;
  for (int k = threadIdx.x; k < nelem; k += 256){
    u16 h = hw[k];
    int e = (h >> 7) & 0xFF;
    if ((h & 0x7FFF) == 0 || (e >= 103 && e <= 130)) local++;
  }
  atomicAdd(&cnt, local);
  __syncthreads();
  if (threadIdx.x == 0) *flag = (cnt >= (nelem * 9) / 10) ? 1 : 0;
}

// ---------------- single prep kernel ----------------
struct PrepArgs {
  const void* csrc[4]; float* cdst[4]; int cn[4];
  const void* ssrc[7]; u16* sdst[7];
  const void* mesrc;   u16* medst;
};
__global__ __launch_bounds__(256) void k_prep(PrepArgs a, const int* __restrict__ flag){
  int y = blockIdx.y;
  int isb = *flag;
  if (y < 4){
    const void* s = a.csrc[y]; float* d = a.cdst[y]; int n = a.cn[y];
    for (int i = blockIdx.x*256 + threadIdx.x; i < n; i += gridDim.x*256)
      d[i] = rdf(s, i, isb);
  } else if (y < 11){
    const void* s = a.ssrc[y-4]; u16* d = a.sdst[y-4];
    int idx = blockIdx.x*256 + threadIdx.x;
    int l = idx >> 14, rem = idx & 16383;
    int j = rem & 7, lane = (rem >> 3) & 63, tn = (rem >> 9) & 7, tk = rem >> 12;
    int k = tk*32 + ((lane >> 4) & 3)*8 + j, n = tn*16 + (lane & 15);
    d[idx] = f2b(rdf(s, (size_t)l*16384 + k*NF + n, isb));
  } else {
    int idx = blockIdx.x*256 + threadIdx.x;
    if (idx >= 3*4096) return;
    int l = idx >> 12, rem = idx & 4095;
    int j = rem & 7, lane = (rem >> 3) & 63, tn = rem >> 9;
    int k = ((lane >> 4) & 3)*8 + j, n = tn*16 + (lane & 15);
    a.medst[idx] = (k < NB) ? f2b(rdf(a.mesrc, (size_t)l*NB*NF + k*NF + n, isb)) : (u16)0;
  }
}

// ---------------- counting sort: hist -> scan -> fused scatter+embed ----------------
__global__ __launch_bounds__(256) void k_hist(const int* __restrict__ ei, int* __restrict__ count){
  int e = blockIdx.x*256 + threadIdx.x;
  if (e < NE) atomicAdd(&count[ei[e]], 1);
}
__global__ __launch_bounds__(256) void k_scan(const int* __restrict__ count,
                                              int* __restrict__ rowptr, int* __restrict__ cursor){
  __shared__ int part[256];
  const int CH = (NN + 255) / 256;
  int t = threadIdx.x;
  int base = t * CH;
  int s = 0;
  for (int k = 0; k < CH; k++){ int i = base + k; if (i < NN) s += count[i]; }
  part[t] = s;
  __syncthreads();
  for (int off = 1; off < 256; off <<= 1){
    int v = (t >= off) ? part[t - off] : 0;
    __syncthreads();
    part[t] += v;
    __syncthreads();
  }
  int run = (t == 0) ? 0 : part[t - 1];
  for (int k = 0; k < CH; k++){
    int i = base + k;
    if (i < NN){ rowptr[i] = run; cursor[i] = run; run += count[i]; }
  }
  if (t == 255) rowptr[NN] = run;
}
__global__ __launch_bounds__(256) void k_scatter_embed(const int* __restrict__ ei,
                                                       int* __restrict__ cursor,
                                                       const float* __restrict__ pos,
                                                       int* __restrict__ iis, int* __restrict__ jjs,
                                                       float* __restrict__ ds,
                                                       float* __restrict__ dirs){
  int e = blockIdx.x * 256 + threadIdx.x;
  if (e >= NE) return;
  int i = ei[e], j = ei[NE + e];
  float dx = pos[j*3+0] - pos[i*3+0];
  float dy = pos[j*3+1] - pos[i*3+1];
  float dz = pos[j*3+2] - pos[i*3+2];
  float d = sqrtf(dx*dx + dy*dy + dz*dz + 1e-12f);
  float inv = 1.0f / d;
  int s = atomicAdd(&cursor[i], 1);
  iis[s] = i; jjs[s] = j;
  ds[s] = d;
  dirs[s*3+0] = dx*inv; dirs[s*3+1] = dy*inv; dirs[s*3+2] = dz*inv;
}
// RBF table: bf16 [NE][32] (20 used, pad 0). Sequential read of ds[e],
// sequential 64 B row write. Values are f2b(identical formula) ->
// bit-identical to the original in-kernel path.
__global__ __launch_bounds__(256) void k_rbf(const float* __restrict__ ds,
                                             u16* __restrict__ rbfb){
  int e = blockIdx.x * 256 + threadIdx.x;
  if (e >= NE) return;
  float d = ds[e];
  float fc = (d < CUT) ? 0.5f*(cosf((float)M_PI*d*(1.0f/CUT)) + 1.0f) : 0.0f;
  u32 row[16];
  #pragma unroll
  for (int kk = 0; kk < 16; kk++){
    int k0 = kk*2, k1 = kk*2 + 1;
    u32 w = 0;
    if (k0 < NB){
      float t0 = (d - CUT*(float)k0/(float)(NB-1)) * ((float)NB/CUT);
      w = (u32)f2b(__expf(-t0*t0) * fc);
    }
    if (k1 < NB){
      float t1 = (d - CUT*(float)k1/(float)(NB-1)) * ((float)NB/CUT);
      w |= ((u32)f2b(__expf(-t1*t1) * fc)) << 16;
    }
    row[kk] = w;
  }
  float4* dst = (float4*)(rbfb + (size_t)e*32);
  #pragma unroll
  for (int jv = 0; jv < 4; jv++)
    dst[jv] = *(const float4*)&row[jv*4];
}

// ---------------- layer-0 node MLP (2-wave tn-split) ----------------
__global__ __launch_bounds__(128, 2) void k_mlp0(
    const int* __restrict__ z, const float* __restrict__ emb,
    float* __restrict__ atom,
    const u16* __restrict__ w1sw, const float* __restrict__ b1,
    const u16* __restrict__ w2sw, const float* __restrict__ b2,
    u32* __restrict__ hb)
{
  __shared__ __align__(16) u16 tileT[16][TPS];
  const int wv = threadIdx.x >> 6;
  const int lane = threadIdx.x & 63;
  const int q = lane >> 4, ln = lane & 15;
  const int n0 = blockIdx.x * 16;
  const int zn = z[n0 + ln];

  floatx4 c1[4];
  #pragma unroll
  for (int t = 0; t < 4; t++) c1[t] = (floatx4){0,0,0,0};
  #pragma unroll
  for (int tk = 0; tk < 4; tk++){
    const float4 u0 = *(const float4*)&emb[(size_t)zn*NF + tk*32 + q*8];
    const float4 u1 = *(const float4*)&emb[(size_t)zn*NF + tk*32 + q*8 + 4];
    if ((tk >> 1) == wv){
      *(float4*)&atom[(size_t)(n0+ln)*NF + tk*32 + q*8]     = u0;
      *(float4*)&atom[(size_t)(n0+ln)*NF + tk*32 + q*8 + 4] = u1;
    }
    short8 a;
    a[0]=(short)f2b(u0.x); a[1]=(short)f2b(u0.y); a[2]=(short)f2b(u0.z); a[3]=(short)f2b(u0.w);
    a[4]=(short)f2b(u1.x); a[5]=(short)f2b(u1.y); a[6]=(short)f2b(u1.z); a[7]=(short)f2b(u1.w);
    #pragma unroll
    for (int t = 0; t < 4; t++){
      short8 b = *(const short8*)(w1sw + (size_t)((tk*8 + wv*4 + t)*64 + lane)*8);
      c1[t] = __builtin_amdgcn_mfma_f32_16x16x32_bf16(a, b, c1[t], 0, 0, 0);
    }
  }
  #pragma unroll
  for (int t = 0; t < 4; t++){
    int n = (wv*4 + t)*16 + ln;
    float bias = b1[n];
    #pragma unroll
    for (int r = 0; r < 4; r++)
      tileT[q*4 + r][n] = f2b(fast_silu(c1[t][r] + bias));
  }
  __syncthreads();   // t1 complete (cross-wave A reads next)
  floatx4 c2[4];
  #pragma unroll
  for (int t = 0; t < 4; t++) c2[t] = (floatx4){0,0,0,0};
  #pragma unroll
  for (int tk = 0; tk < 4; tk++){
    short8 a = *(const short8*)&tileT[ln][tk*32 + q*8];
    #pragma unroll
    for (int t = 0; t < 4; t++){
      short8 b = *(const short8*)(w2sw + (size_t)((tk*8 + wv*4 + t)*64 + lane)*8);
      c2[t] = __builtin_amdgcn_mfma_f32_16x16x32_bf16(a, b, c2[t], 0, 0, 0);
    }
  }
  #pragma unroll
  for (int t = 0; t < 4; t++){
    float bias = b2[(wv*4 + t)*16 + ln];
    #pragma unroll
    for (int r = 0; r < 4; r++)
      ((u16*)hb)[(((size_t)(n0 + q*4 + r))*64 + t*16 + ln)*2 + wv] = f2b(c2[t][r] + bias);
  }
}

// Segment flush: each ACTIVE lane owns ONE column cc of tileF. Wave-uniform
// SGPR boundary bitmask (computed once via __ballot), node ids via readlane
// with literal lane indices, fully unrolled scalar-branch loop.
#define SEGFLUSH(ADDR_EXPR)                                               \
  {                                                                       \
    float s_ = 0.f;                                                       \
    _Pragma("unroll")                                                     \
    for (int m_ = 0; m_ < 16; m_++){                                      \
      s_ += tileF[m_][cc];                                                \
      if (m_ == 15 || ((bmask >> (m_ + 1)) & 1u)){                        \
        int ii_ = __builtin_amdgcn_readlane(curii, m_);                   \
        float* p_ = (ADDR_EXPR);                                          \
        atomicAdd(p_ + cc, s_);                                           \
        s_ = 0.f;                                                         \
      }                                                                   \
    }                                                                     \
  }

// ---------------- MFMA edge kernel (v16: 4-wave split + hoisted fjw) ----------------
// v15 structure (4-wave tn-split, 3 __syncthreads, wave-local tileF) with
// the d-loop's fjw gathers hoisted into one 24-dword burst after P4. v8's
// hoist spilled at a 64-VGPR / 4-wide base; here base is 36 VGPR / 2-wide,
// so the +24 VGPR fits (~60 < any occupancy cliff). Removes 2 serial L2
// round-trips per wave.
// d-flush goes directly to force: safe because force_old is read exclusively
// via the forceb bf16 snapshot, never via force.
__global__ __launch_bounds__(256, 2) void k_edge_mfma(
    const int* __restrict__ iis, const int* __restrict__ jjs,
    const u16* __restrict__ rbfb, const float* __restrict__ dirs,
    const u32* __restrict__ hb,
    const u16* __restrict__ mesw,
    const u16* __restrict__ w11sw, const u16* __restrict__ w12sw,
    const u16* __restrict__ w21sw, const u16* __restrict__ w22sw,
    float* __restrict__ atom, const u32* __restrict__ forceb, float* __restrict__ force)
{
  __shared__ __align__(16) u16 tileM[16][TPS];
  __shared__ __align__(16) float tileF[16][TPF];
  u16* tileFu = (u16*)&tileF[0][0];   // t1 staging alias (16 x TPS u16 fits in 16 x TPF fp32)

  const int w = threadIdx.x >> 6;           // 0..3: tn-pair owner
  const int lane = threadIdx.x & 63;
  const int q = lane >> 4, ln = lane & 15;
  const int half = w >> 1;                  // packed-word half (0=lo,1=hi)
  const int wt = (w & 1) * 2;               // packed-word base index
  // XCD-aware swizzle (grid 10000 % 8 == 0)
  const int bid = (blockIdx.x & 7) * (gridDim.x >> 3) + (blockIdx.x >> 3);
  const int e0 = bid * 16;
  const int cc = w*32 + (lane & 31);        // flush column (valid for lane<32)

  // Segment structure, computed once (identical in all waves).
  const int l16 = lane & 15;
  int curii = iis[e0 + l16];
  int previi = (l16 == 0) ? ~curii : iis[e0 + l16 - 1];
  const u32 bmask = (u32)__ballot(lane < 16 && (curii != previi));

  int iiR[4], jjR[4];
  float dirR[4][3];
  #pragma unroll
  for (int r = 0; r < 4; r++){
    int s = e0 + q*4 + r;
    iiR[r] = iis[s]; jjR[r] = jjs[s];
    dirR[r][0] = dirs[s*3+0]; dirR[r][1] = dirs[s*3+1]; dirR[r][2] = dirs[s*3+2];
  }

  // h-gathers: only the 2 packed words this wave's tn-pair needs
  u32 hiw[4][2], hjw[4][2];
  #pragma unroll
  for (int r = 0; r < 4; r++)
    #pragma unroll
    for (int t = 0; t < 2; t++){
      hiw[r][t] = hb[(size_t)iiR[r]*64 + (wt + t)*16 + ln];
      hjw[r][t] = hb[(size_t)jjR[r]*64 + (wt + t)*16 + ln];
    }

  // A-fragment: precomputed rbf row (lane holds edge e0+ln, k-slice q*8..q*8+7)
  short8 a_rbf = *(const short8*)(rbfb + (size_t)(e0 + ln)*32 + q*8);

  // P1: me = rbf @ meW (own 2 tn); msg -> tileF (fp32, own cols) + tileM (bf16)
  #pragma unroll
  for (int t = 0; t < 2; t++){
    const int tn_g = w*2 + t;
    short8 b = *(const short8*)(mesw + (size_t)(tn_g*64 + lane)*8);
    floatx4 c = {0.f,0.f,0.f,0.f};
    c = __builtin_amdgcn_mfma_f32_16x16x32_bf16(a_rbf, b, c, 0, 0, 0);
    const int n = tn_g*16 + ln;
    #pragma unroll
    for (int r = 0; r < 4; r++){
      float hi_ = half ? hi_bf(hiw[r][t]) : lo_bf(hiw[r][t]);
      float hj_ = half ? hi_bf(hjw[r][t]) : lo_bf(hjw[r][t]);
      float mv = c[r] * hi_ * hj_;
      tileF[q*4 + r][n] = mv;
      tileM[q*4 + r][n] = f2b(mv);
    }
  }

  // atom flush (lanes 0-31; tileF own cols, wave-local -> no pre-barrier)
  if (lane < 32){
    SEGFLUSH(&atom[(size_t)ii_ * NF])
  }

  __syncthreads();   // B1: msg complete in tileM

  // P2: one A-read feeds both c2 = msg@w21 and c1 = msg@w11 (own 2 tn)
  floatx4 c2[2], c1[2];
  #pragma unroll
  for (int t = 0; t < 2; t++){ c2[t] = (floatx4){0,0,0,0}; c1[t] = (floatx4){0,0,0,0}; }
  #pragma unroll
  for (int tk = 0; tk < 4; tk++){
    short8 a = *(const short8*)&tileM[ln][tk*32 + q*8];
    #pragma unroll
    for (int t = 0; t < 2; t++){
      const int tn_g = w*2 + t;
      short8 b2 = *(const short8*)(w21sw + (size_t)((tk*8 + tn_g)*64 + lane)*8);
      c2[t] = __builtin_amdgcn_mfma_f32_16x16x32_bf16(a, b2, c2[t], 0, 0, 0);
      short8 b1 = *(const short8*)(w11sw + (size_t)((tk*8 + tn_g)*64 + lane)*8);
      c1[t] = __builtin_amdgcn_mfma_f32_16x16x32_bf16(a, b1, c1[t], 0, 0, 0);
    }
  }
  #pragma unroll
  for (int t = 0; t < 2; t++){
    const int n = (w*2 + t)*16 + ln;
    #pragma unroll
    for (int r = 0; r < 4; r++){
      tileFu[(q*4 + r)*TPS + n] = f2b(fast_silu(c1[t][r]));   // t1 staging
      c2[t][r] = fast_silu(c2[t][r]);
    }
  }

  __syncthreads();   // B2: t1 complete (and all msg reads done)

  // P3: g1 = t1 @ w12; then t2 -> tileM (msg dead after B2)
  floatx4 g1[2];
  #pragma unroll
  for (int t = 0; t < 2; t++) g1[t] = (floatx4){0,0,0,0};
  #pragma unroll
  for (int tk = 0; tk < 4; tk++){
    short8 a = *(const short8*)&tileFu[(size_t)ln*TPS + tk*32 + q*8];
    #pragma unroll
    for (int t = 0; t < 2; t++){
      short8 b = *(const short8*)(w12sw + (size_t)((tk*8 + w*2 + t)*64 + lane)*8);
      g1[t] = __builtin_amdgcn_mfma_f32_16x16x32_bf16(a, b, g1[t], 0, 0, 0);
    }
  }
  #pragma unroll
  for (int t = 0; t < 2; t++){
    const int n = (w*2 + t)*16 + ln;
    #pragma unroll
    for (int r = 0; r < 4; r++) tileM[q*4 + r][n] = f2b(c2[t][r]);   // t2
  }

  __syncthreads();   // B3: t2 complete (and all t1 reads done)

  // P4: g2 = t2 @ w22
  floatx4 g2[2];
  #pragma unroll
  for (int t = 0; t < 2; t++) g2[t] = (floatx4){0,0,0,0};
  #pragma unroll
  for (int tk = 0; tk < 4; tk++){
    short8 a = *(const short8*)&tileM[ln][tk*32 + q*8];
    #pragma unroll
    for (int t = 0; t < 2; t++){
      short8 b = *(const short8*)(w22sw + (size_t)((tk*8 + w*2 + t)*64 + lane)*8);
      g2[t] = __builtin_amdgcn_mfma_f32_16x16x32_bf16(a, b, g2[t], 0, 0, 0);
    }
  }

  // hoisted fjw gathers for all 3 d (24 dwords/lane, one pipelined burst;
  // +24 VGPR on a 36-VGPR base — no spill headroom issue)
  u32 fjw[3][4][2];
  #pragma unroll
  for (int d = 0; d < 3; d++)
    #pragma unroll
    for (int r = 0; r < 4; r++)
      #pragma unroll
      for (int t = 0; t < 2; t++)
        fjw[d][r][t] = forceb[((size_t)jjR[r]*3 + d)*64 + (wt + t)*16 + ln];

  // three d-passes: tileF (own cols, wave-local) <- g1*dir + g2*force_old[j];
  // flush -> force (lanes 0-31)
  #pragma unroll
  for (int d = 0; d < 3; d++){
    #pragma unroll
    for (int t = 0; t < 2; t++){
      const int n = (w*2 + t)*16 + ln;
      #pragma unroll
      for (int r = 0; r < 4; r++){
        float fj = half ? hi_bf(fjw[d][r][t]) : lo_bf(fjw[d][r][t]);
        tileF[q*4 + r][n] = g1[t][r]*dirR[r][d] + g2[t][r]*fj;
      }
    }
    if (lane < 32){
      SEGFLUSH(&force[((size_t)ii_*3 + d)*NF])
    }
  }
}

// ---------------- fused node kernel (4-wave tn-split, 3-d batched staging) ----------------
__global__ __launch_bounds__(256, 2) void k_node(
    const float* __restrict__ force,
    const u16* __restrict__ eusw, u32* __restrict__ forceb,
    float* __restrict__ atom,
    const u16* __restrict__ w1sw, const float* __restrict__ b1,
    const u16* __restrict__ w2sw, const float* __restrict__ b2,
    u32* __restrict__ hb, int do_mlp)
{
  __shared__ __align__(16) u16 tileM3[3][16][TPS];
  __shared__ __align__(16) float tileF3[3][16][TPF];
  const int w = threadIdx.x >> 6;           // 0..3
  const int lane = threadIdx.x & 63;
  const int q = lane >> 4, ln = lane & 15;
  const int n0 = blockIdx.x * 16;
  const int cc2 = threadIdx.x & 127;        // staging column
  const int mh  = (threadIdx.x >> 7) * 8;   // staging row-half base

  // stage all 3 d upfront: 24 coalesced loads/thread in one pipelined burst
  #pragma unroll
  for (int d = 0; d < 3; d++)
    #pragma unroll
    for (int m8 = 0; m8 < 8; m8++){
      int m = mh + m8;
      size_t idx = ((size_t)(n0+m)*3 + d)*NF + cc2;
      float v = force[idx];
      if (do_mlp)
        ((u16*)forceb)[(((size_t)(n0+m)*3 + d)*64 + (cc2 & 63))*2 + (cc2 >> 6)] = f2b(v);
      tileM3[d][m][cc2] = f2b(v);
      tileF3[d][m][cc2] = v;
    }
  __syncthreads();   // all tiles staged

  float acc[2][4];
  #pragma unroll
  for (int t = 0; t < 2; t++)
    #pragma unroll
    for (int r = 0; r < 4; r++) acc[t][r] = 0.f;

  #pragma unroll
  for (int d = 0; d < 3; d++){
    floatx4 c[2];
    #pragma unroll
    for (int t = 0; t < 2; t++) c[t] = (floatx4){0,0,0,0};
    #pragma unroll
    for (int tk = 0; tk < 4; tk++){
      short8 a = *(const short8*)&tileM3[d][ln][tk*32 + q*8];
      #pragma unroll
      for (int t = 0; t < 2; t++){
        short8 b = *(const short8*)(eusw + (size_t)((tk*8 + w*2 + t)*64 + lane)*8);
        c[t] = __builtin_amdgcn_mfma_f32_16x16x32_bf16(a, b, c[t], 0, 0, 0);
      }
    }
    #pragma unroll
    for (int t = 0; t < 2; t++){
      int n = (w*2 + t)*16 + ln;
      #pragma unroll
      for (int r = 0; r < 4; r++)
        acc[t][r] += tileF3[d][q*4 + r][n] * c[t][r];
    }
  }

  float anew[2][4];
  #pragma unroll
  for (int t = 0; t < 2; t++){
    int n = (w*2 + t)*16 + ln;
    #pragma unroll
    for (int r = 0; r < 4; r++){
      size_t idx = (size_t)(n0 + q*4 + r)*NF + n;
      float v = atom[idx] + acc[t][r];
      atom[idx] = v;
      anew[t][r] = v;
    }
  }
  if (!do_mlp) return;

  u16 (*tile)[TPS] = tileM3[0];
  __syncthreads();   // eu A-reads of tileM3[0] (all waves) done before overwrite
  #pragma unroll
  for (int t = 0; t < 2; t++){
    int n = (w*2 + t)*16 + ln;
    #pragma unroll
    for (int r = 0; r < 4; r++) tile[q*4 + r][n] = f2b(anew[t][r]);
  }
  __syncthreads();   // anew staged
  floatx4 c1[2];
  #pragma unroll
  for (int t = 0; t < 2; t++) c1[t] = (floatx4){0,0,0,0};
  #pragma unroll
  for (int tk = 0; tk < 4; tk++){
    short8 a = *(const short8*)&tile[ln][tk*32 + q*8];
    #pragma unroll
    for (int t = 0; t < 2; t++){
      short8 b = *(const short8*)(w1sw + (size_t)((tk*8 + w*2 + t)*64 + lane)*8);
      c1[t] = __builtin_amdgcn_mfma_f32_16x16x32_bf16(a, b, c1[t], 0, 0, 0);
    }
  }
  __syncthreads();   // c1 A-reads done before silu overwrite
  #pragma unroll
  for (int t = 0; t < 2; t++){
    int n = (w*2 + t)*16 + ln;
    float bias = b1[n];
    #pragma unroll
    for (int r = 0; r < 4; r++)
      tile[q*4 + r][n] = f2b(fast_silu(c1[t][r] + bias));
  }
  __syncthreads();   // t1 staged
  floatx4 c2[2];
  #pragma unroll
  for (int t = 0; t < 2; t++) c2[t] = (floatx4){0,0,0,0};
  #pragma unroll
  for (int tk = 0; tk < 4; tk++){
    short8 a = *(const short8*)&tile[ln][tk*32 + q*8];
    #pragma unroll
    for (int t = 0; t < 2; t++){
      short8 b = *(const short8*)(w2sw + (size_t)((tk*8 + w*2 + t)*64 + lane)*8);
      c2[t] = __builtin_amdgcn_mfma_f32_16x16x32_bf16(a, b, c2[t], 0, 0, 0);
    }
  }
  #pragma unroll
  for (int t = 0; t < 2; t++){
    int tn = w*2 + t;
    float bias = b2[tn*16 + ln];
    #pragma unroll
    for (int r = 0; r < 4; r++)
      ((u16*)hb)[(((size_t)(n0 + q*4 + r))*64 + (tn & 3)*16 + ln)*2 + (tn >> 2)] = f2b(c2[t][r] + bias);
  }
}

// ---------------- write out ----------------
__global__ __launch_bounds__(256) void k_writeout(const float* __restrict__ atom,
                                                  const float* __restrict__ force,
                                                  void* __restrict__ out,
                                                  const int* __restrict__ flag){
  int idx = blockIdx.x * 256 + threadIdx.x;
  const int na = NN * NF;
  const int tot = na + NN * 3 * NF;
  if (idx >= tot) return;
  float v = (idx < na) ? atom[idx] : force[idx - na];
  if (*flag) ((__hip_bfloat16*)out)[idx] = __float2bfloat16(v);
  else       ((float*)out)[idx] = v;
}

extern "C" void kernel_launch(void* const* d_in, const int* in_sizes, int n_in,
                              void* d_out, int out_size, void* d_ws, size_t ws_size,
                              hipStream_t stream){
  const int* z    = (const int*)d_in[0];
  const void* pos = d_in[1];
  // d_in[2] cell, d_in[3] batch: numerically dead (sym == I)
  const int* ei   = (const int*)d_in[4];
  const void* emb   = d_in[5];
  const void* mnpW1 = d_in[6];
  const void* mnpb1 = d_in[7];
  const void* mnpW2 = d_in[8];
  const void* mnpb2 = d_in[9];
  const void* meW   = d_in[10];
  const void* em1W1 = d_in[11];
  const void* em1W2 = d_in[12];
  const void* em2W1 = d_in[13];
  const void* em2W2 = d_in[14];
  const void* euW   = d_in[15];

  float* base  = (float*)d_ws;
  int*   flag  = (int*)d_ws;                  // 4 floats reserved
  float* atom   = base + 4;                   // NN*NF
  float* force  = atom   + NN*NF;             // NN*3*NF (edge atomics accumulate here)
  u32*   forceb = (u32*)(force + (size_t)NN*3*NF);   // NN*3*64
  int*   count  = (int*)(forceb + (size_t)NN*3*64);  // NN
  float* ds    = (float*)(count + NN);        // NE
  float* dirs  = ds + NE;                     // 3*NE
  float* posf  = dirs + 3*NE;
  float* embf  = posf + NN*3;
  float* b1f   = embf + 119*NF;
  float* b2f_  = b1f + 3*NF;
  u32*   hb    = (u32*)(b2f_ + 3*NF);
  u16*   mesw  = (u16*)(hb + (size_t)NN*64);
  u16*   w11sw = mesw  + 3*4096;
  u16*   w12sw = w11sw + 3*16384;
  u16*   w21sw = w12sw + 3*16384;
  u16*   w22sw = w21sw + 3*16384;
  u16*   w1sw  = w22sw + 3*16384;
  u16*   w2sw  = w1sw  + 3*16384;
  u16*   eusw  = w2sw  + 3*16384;
  int* rowptr  = (int*)(eusw + 3*16384);
  int* cursor  = rowptr + NN + 1;
  int* iis     = cursor + NN;
  int* jjs     = iis + NE;
  u16* rbfb    = (u16*)(jjs + NE);            // NE*32 bf16 (10.24 MB)

  k_detect<<<1, 256, 0, stream>>>(meW, 3*NB*NF, flag);

  // zero force + forceb + count (contiguous)
  hipMemsetAsync(force, 0, ((size_t)NN*3*NF + (size_t)NN*3*64 + NN)*4, stream);

  PrepArgs pa;
  pa.csrc[0]=pos;   pa.cdst[0]=posf; pa.cn[0]=NN*3;
  pa.csrc[1]=emb;   pa.cdst[1]=embf; pa.cn[1]=119*NF;
  pa.csrc[2]=mnpb1; pa.cdst[2]=b1f;  pa.cn[2]=3*NF;
  pa.csrc[3]=mnpb2; pa.cdst[3]=b2f_; pa.cn[3]=3*NF;
  pa.ssrc[0]=em1W1; pa.sdst[0]=w11sw;
  pa.ssrc[1]=em1W2; pa.sdst[1]=w12sw;
  pa.ssrc[2]=em2W1; pa.sdst[2]=w21sw;
  pa.ssrc[3]=em2W2; pa.sdst[3]=w22sw;
  pa.ssrc[4]=mnpW1; pa.sdst[4]=w1sw;
  pa.ssrc[5]=mnpW2; pa.sdst[5]=w2sw;
  pa.ssrc[6]=euW;   pa.sdst[6]=eusw;
  pa.mesrc=meW;     pa.medst=mesw;
  k_prep<<<dim3(192,12), 256, 0, stream>>>(pa, flag);

  k_hist         <<<(NE+255)/256, 256, 0, stream>>>(ei, count);
  k_scan         <<<1, 256, 0, stream>>>(count, rowptr, cursor);
  k_scatter_embed<<<(NE+255)/256, 256, 0, stream>>>(ei, cursor, posf, iis, jjs, ds, dirs);
  k_rbf          <<<(NE+255)/256, 256, 0, stream>>>(ds, rbfb);

  k_mlp0<<<NN/16, 128, 0, stream>>>(z, embf, atom, w1sw, b1f, w2sw, b2f_, hb);
  for (int l = 0; l < 3; l++){
    k_edge_mfma<<<NE/16, 256, 0, stream>>>(iis, jjs, rbfb, dirs, hb,
        mesw  + (size_t)l*4096,
        w11sw + (size_t)l*16384, w12sw + (size_t)l*16384,
        w21sw + (size_t)l*16384, w22sw + (size_t)l*16384,
        atom, forceb, force);
    int nl = l + 1;
    k_node<<<NN/16, 256, 0, stream>>>(force,
        eusw + (size_t)l*16384, forceb, atom,
        w1sw + (size_t)(nl%3)*16384, b1f + (size_t)(nl%3)*NF,
        w2sw + (size_t)(nl%3)*16384, b2f_ + (size_t)(nl%3)*NF,
        hb, (l < 2) ? 1 : 0);
  }

  k_writeout<<<(NN*NF + NN*3*NF + 255)/256, 256, 0, stream>>>(atom, force, d_out, flag);
}

// Round 18
// 483.160 us; speedup vs baseline: 1.0500x; 1.0500x over previous
//
#include <hip/hip_runtime.h>
#include <hip/hip_bf16.h>
#include <math.h>

#define NN 10000
#define NE 160000
#define NF 128
#define NB 20
#define CUT 5.0f
#define TPS 136   // u16 tile row stride
#define TPF 132   // fp32 tile row stride

typedef __attribute__((ext_vector_type(8))) short short8;
typedef __attribute__((ext_vector_type(4))) float floatx4;
typedef unsigned short u16;
typedef unsigned int u32;

__device__ __forceinline__ u16 f2b(float x){
  union { __hip_bfloat16 b; u16 u; } cv;
  cv.b = __float2bfloat16(x);
  return cv.u;
}
__device__ __forceinline__ float lo_bf(u32 w){ return __uint_as_float(w << 16); }
__device__ __forceinline__ float hi_bf(u32 w){ return __uint_as_float(w & 0xFFFF0000u); }
__device__ __forceinline__ float fast_silu(float v){
  return v * __builtin_amdgcn_rcpf(1.f + __expf(-v));
}
__device__ __forceinline__ float rdf(const void* p, size_t i, int isb){
  return isb ? __bfloat162float(((const __hip_bfloat16*)p)[i]) : ((const float*)p)[i];
}

// ---------------- dtype detector: 1=bf16, 0=fp32 ----------------
__global__ __launch_bounds__(256) void k_detect(const void* __restrict__ w, int nelem,
                                                int* __restrict__ flag){
  __shared__ int cnt;
  if (threadIdx.x == 0) cnt = 0;
  __syncthreads();
  const u16* hw = (const u16*)w;
  int local = 0;
  for (int k = threadIdx.x; k < nelem; k += 256){
    u16 h = hw[k];
    int e = (h >> 7) & 0xFF;
    if ((h & 0x7FFF) == 0 || (e >= 103 && e <= 130)) local++;
  }
  atomicAdd(&cnt, local);
  __syncthreads();
  if (threadIdx.x == 0) *flag = (cnt >= (nelem * 9) / 10) ? 1 : 0;
}

// ---------------- single prep kernel ----------------
struct PrepArgs {
  const void* csrc[4]; float* cdst[4]; int cn[4];
  const void* ssrc[7]; u16* sdst[7];
  const void* mesrc;   u16* medst;
};
__global__ __launch_bounds__(256) void k_prep(PrepArgs a, const int* __restrict__ flag){
  int y = blockIdx.y;
  int isb = *flag;
  if (y < 4){
    const void* s = a.csrc[y]; float* d = a.cdst[y]; int n = a.cn[y];
    for (int i = blockIdx.x*256 + threadIdx.x; i < n; i += gridDim.x*256)
      d[i] = rdf(s, i, isb);
  } else if (y < 11){
    const void* s = a.ssrc[y-4]; u16* d = a.sdst[y-4];
    int idx = blockIdx.x*256 + threadIdx.x;
    int l = idx >> 14, rem = idx & 16383;
    int j = rem & 7, lane = (rem >> 3) & 63, tn = (rem >> 9) & 7, tk = rem >> 12;
    int k = tk*32 + ((lane >> 4) & 3)*8 + j, n = tn*16 + (lane & 15);
    d[idx] = f2b(rdf(s, (size_t)l*16384 + k*NF + n, isb));
  } else {
    int idx = blockIdx.x*256 + threadIdx.x;
    if (idx >= 3*4096) return;
    int l = idx >> 12, rem = idx & 4095;
    int j = rem & 7, lane = (rem >> 3) & 63, tn = rem >> 9;
    int k = ((lane >> 4) & 3)*8 + j, n = tn*16 + (lane & 15);
    a.medst[idx] = (k < NB) ? f2b(rdf(a.mesrc, (size_t)l*NB*NF + k*NF + n, isb)) : (u16)0;
  }
}

// ---------------- counting sort: hist -> scan -> fused scatter+embed ----------------
__global__ __launch_bounds__(256) void k_hist(const int* __restrict__ ei, int* __restrict__ count){
  int e = blockIdx.x*256 + threadIdx.x;
  if (e < NE) atomicAdd(&count[ei[e]], 1);
}
__global__ __launch_bounds__(256) void k_scan(const int* __restrict__ count,
                                              int* __restrict__ rowptr, int* __restrict__ cursor){
  __shared__ int part[256];
  const int CH = (NN + 255) / 256;
  int t = threadIdx.x;
  int base = t * CH;
  int s = 0;
  for (int k = 0; k < CH; k++){ int i = base + k; if (i < NN) s += count[i]; }
  part[t] = s;
  __syncthreads();
  for (int off = 1; off < 256; off <<= 1){
    int v = (t >= off) ? part[t - off] : 0;
    __syncthreads();
    part[t] += v;
    __syncthreads();
  }
  int run = (t == 0) ? 0 : part[t - 1];
  for (int k = 0; k < CH; k++){
    int i = base + k;
    if (i < NN){ rowptr[i] = run; cursor[i] = run; run += count[i]; }
  }
  if (t == 255) rowptr[NN] = run;
}
__global__ __launch_bounds__(256) void k_scatter_embed(const int* __restrict__ ei,
                                                       int* __restrict__ cursor,
                                                       const float* __restrict__ pos,
                                                       int* __restrict__ iis, int* __restrict__ jjs,
                                                       float* __restrict__ ds,
                                                       float* __restrict__ dirs){
  int e = blockIdx.x * 256 + threadIdx.x;
  if (e >= NE) return;
  int i = ei[e], j = ei[NE + e];
  float dx = pos[j*3+0] - pos[i*3+0];
  float dy = pos[j*3+1] - pos[i*3+1];
  float dz = pos[j*3+2] - pos[i*3+2];
  float d = sqrtf(dx*dx + dy*dy + dz*dz + 1e-12f);
  float inv = 1.0f / d;
  int s = atomicAdd(&cursor[i], 1);
  iis[s] = i; jjs[s] = j;
  ds[s] = d;
  dirs[s*3+0] = dx*inv; dirs[s*3+1] = dy*inv; dirs[s*3+2] = dz*inv;
}
// RBF table: bf16 [NE][32] (20 used, pad 0). Sequential read of ds[e],
// sequential 64 B row write. Values are f2b(identical formula) ->
// bit-identical to the original in-kernel path.
__global__ __launch_bounds__(256) void k_rbf(const float* __restrict__ ds,
                                             u16* __restrict__ rbfb){
  int e = blockIdx.x * 256 + threadIdx.x;
  if (e >= NE) return;
  float d = ds[e];
  float fc = (d < CUT) ? 0.5f*(cosf((float)M_PI*d*(1.0f/CUT)) + 1.0f) : 0.0f;
  u32 row[16];
  #pragma unroll
  for (int kk = 0; kk < 16; kk++){
    int k0 = kk*2, k1 = kk*2 + 1;
    u32 w = 0;
    if (k0 < NB){
      float t0 = (d - CUT*(float)k0/(float)(NB-1)) * ((float)NB/CUT);
      w = (u32)f2b(__expf(-t0*t0) * fc);
    }
    if (k1 < NB){
      float t1 = (d - CUT*(float)k1/(float)(NB-1)) * ((float)NB/CUT);
      w |= ((u32)f2b(__expf(-t1*t1) * fc)) << 16;
    }
    row[kk] = w;
  }
  float4* dst = (float4*)(rbfb + (size_t)e*32);
  #pragma unroll
  for (int jv = 0; jv < 4; jv++)
    dst[jv] = *(const float4*)&row[jv*4];
}

// ---------------- layer-0 node MLP (2-wave tn-split) ----------------
__global__ __launch_bounds__(128, 2) void k_mlp0(
    const int* __restrict__ z, const float* __restrict__ emb,
    float* __restrict__ atom,
    const u16* __restrict__ w1sw, const float* __restrict__ b1,
    const u16* __restrict__ w2sw, const float* __restrict__ b2,
    u32* __restrict__ hb)
{
  __shared__ __align__(16) u16 tileT[16][TPS];
  const int wv = threadIdx.x >> 6;
  const int lane = threadIdx.x & 63;
  const int q = lane >> 4, ln = lane & 15;
  const int n0 = blockIdx.x * 16;
  const int zn = z[n0 + ln];

  floatx4 c1[4];
  #pragma unroll
  for (int t = 0; t < 4; t++) c1[t] = (floatx4){0,0,0,0};
  #pragma unroll
  for (int tk = 0; tk < 4; tk++){
    const float4 u0 = *(const float4*)&emb[(size_t)zn*NF + tk*32 + q*8];
    const float4 u1 = *(const float4*)&emb[(size_t)zn*NF + tk*32 + q*8 + 4];
    if ((tk >> 1) == wv){
      *(float4*)&atom[(size_t)(n0+ln)*NF + tk*32 + q*8]     = u0;
      *(float4*)&atom[(size_t)(n0+ln)*NF + tk*32 + q*8 + 4] = u1;
    }
    short8 a;
    a[0]=(short)f2b(u0.x); a[1]=(short)f2b(u0.y); a[2]=(short)f2b(u0.z); a[3]=(short)f2b(u0.w);
    a[4]=(short)f2b(u1.x); a[5]=(short)f2b(u1.y); a[6]=(short)f2b(u1.z); a[7]=(short)f2b(u1.w);
    #pragma unroll
    for (int t = 0; t < 4; t++){
      short8 b = *(const short8*)(w1sw + (size_t)((tk*8 + wv*4 + t)*64 + lane)*8);
      c1[t] = __builtin_amdgcn_mfma_f32_16x16x32_bf16(a, b, c1[t], 0, 0, 0);
    }
  }
  #pragma unroll
  for (int t = 0; t < 4; t++){
    int n = (wv*4 + t)*16 + ln;
    float bias = b1[n];
    #pragma unroll
    for (int r = 0; r < 4; r++)
      tileT[q*4 + r][n] = f2b(fast_silu(c1[t][r] + bias));
  }
  __syncthreads();   // t1 complete (cross-wave A reads next)
  floatx4 c2[4];
  #pragma unroll
  for (int t = 0; t < 4; t++) c2[t] = (floatx4){0,0,0,0};
  #pragma unroll
  for (int tk = 0; tk < 4; tk++){
    short8 a = *(const short8*)&tileT[ln][tk*32 + q*8];
    #pragma unroll
    for (int t = 0; t < 4; t++){
      short8 b = *(const short8*)(w2sw + (size_t)((tk*8 + wv*4 + t)*64 + lane)*8);
      c2[t] = __builtin_amdgcn_mfma_f32_16x16x32_bf16(a, b, c2[t], 0, 0, 0);
    }
  }
  #pragma unroll
  for (int t = 0; t < 4; t++){
    float bias = b2[(wv*4 + t)*16 + ln];
    #pragma unroll
    for (int r = 0; r < 4; r++)
      ((u16*)hb)[(((size_t)(n0 + q*4 + r))*64 + t*16 + ln)*2 + wv] = f2b(c2[t][r] + bias);
  }
}

// Segment flush: each lane owns ONE column cc of tileF. Wave-uniform SGPR
// boundary bitmask (computed once via __ballot), node ids via readlane with
// literal lane indices, fully unrolled scalar-branch loop.
#define SEGFLUSH(ADDR_EXPR)                                               \
  {                                                                       \
    float s_ = 0.f;                                                       \
    _Pragma("unroll")                                                     \
    for (int m_ = 0; m_ < 16; m_++){                                      \
      s_ += tileF[m_][cc];                                                \
      if (m_ == 15 || ((bmask >> (m_ + 1)) & 1u)){                        \
        int ii_ = __builtin_amdgcn_readlane(curii, m_);                   \
        float* p_ = (ADDR_EXPR);                                          \
        atomicAdd(p_ + cc, s_);                                           \
        s_ = 0.f;                                                         \
      }                                                                   \
    }                                                                     \
  }

// ---------------- MFMA edge kernel (final: v12/v14 proven config) ----------------
// 2-wave tn-split, tileM + tileF (tileFu alias for t1), 3 __syncthreads,
// per-d fjw gathers, rbf-table A-fragment, d-flush direct to force.
// Measured 92.9-101 us across runs; invariant to occupancy doubling (v15)
// and gather hoisting (v16) -> latency-structure plateau for this
// decomposition. Safe because force_old is read exclusively via the forceb
// bf16 snapshot, never via force.
__global__ __launch_bounds__(128, 4) void k_edge_mfma(
    const int* __restrict__ iis, const int* __restrict__ jjs,
    const u16* __restrict__ rbfb, const float* __restrict__ dirs,
    const u32* __restrict__ hb,
    const u16* __restrict__ mesw,
    const u16* __restrict__ w11sw, const u16* __restrict__ w12sw,
    const u16* __restrict__ w21sw, const u16* __restrict__ w22sw,
    float* __restrict__ atom, const u32* __restrict__ forceb, float* __restrict__ force)
{
  __shared__ __align__(16) u16 tileM[16][TPS];
  __shared__ __align__(16) float tileF[16][TPF];
  u16* tileFu = (u16*)&tileF[0][0];   // t1 staging alias (16 x TPS u16 fits in 16 x TPF fp32)

  const int wv = threadIdx.x >> 6;          // column-half owner
  const int lane = threadIdx.x & 63;
  const int q = lane >> 4, ln = lane & 15;
  // XCD-aware swizzle (grid 10000 % 8 == 0)
  const int bid = (blockIdx.x & 7) * (gridDim.x >> 3) + (blockIdx.x >> 3);
  const int e0 = bid * 16;
  const int cc = wv*64 + lane;              // flush column this lane owns

  // Segment structure, computed once (identical in both waves).
  const int l16 = lane & 15;
  int curii = iis[e0 + l16];
  int previi = (l16 == 0) ? ~curii : iis[e0 + l16 - 1];
  const u32 bmask = (u32)__ballot(lane < 16 && (curii != previi));

  int iiR[4], jjR[4];
  float dirR[4][3];
  #pragma unroll
  for (int r = 0; r < 4; r++){
    int s = e0 + q*4 + r;
    iiR[r] = iis[s]; jjR[r] = jjs[s];
    dirR[r][0] = dirs[s*3+0]; dirR[r][1] = dirs[s*3+1]; dirR[r][2] = dirs[s*3+2];
  }

  u32 hiw[4][4], hjw[4][4];
  #pragma unroll
  for (int r = 0; r < 4; r++)
    #pragma unroll
    for (int t = 0; t < 4; t++){
      hiw[r][t] = hb[(size_t)iiR[r]*64 + t*16 + ln];
      hjw[r][t] = hb[(size_t)jjR[r]*64 + t*16 + ln];
    }

  // A-fragment: precomputed rbf row (lane holds edge e0+ln, k-slice q*8..q*8+7)
  short8 a_rbf = *(const short8*)(rbfb + (size_t)(e0 + ln)*32 + q*8);

  // P1: me = rbf @ meW (own 4 tn); msg -> tileF (fp32) + tileM (bf16), own cols
  #pragma unroll
  for (int t = 0; t < 4; t++){
    const int tn_g = wv*4 + t;
    short8 b = *(const short8*)(mesw + (size_t)(tn_g*64 + lane)*8);
    floatx4 c = {0.f,0.f,0.f,0.f};
    c = __builtin_amdgcn_mfma_f32_16x16x32_bf16(a_rbf, b, c, 0, 0, 0);
    const int n = tn_g*16 + ln;
    #pragma unroll
    for (int r = 0; r < 4; r++){
      float hi_ = wv ? hi_bf(hiw[r][t]) : lo_bf(hiw[r][t]);
      float hj_ = wv ? hi_bf(hjw[r][t]) : lo_bf(hjw[r][t]);
      float mv = c[r] * hi_ * hj_;
      tileF[q*4 + r][n] = mv;
      tileM[q*4 + r][n] = f2b(mv);
    }
  }

  // atom flush (own cols; reads precede barrier 1 -> alias-safe)
  SEGFLUSH(&atom[(size_t)ii_ * NF])

  __syncthreads();   // B1: msg complete in tileM

  // P2: one A-read feeds both c2 = msg@w21 and c1 = msg@w11 (own 4 tn)
  floatx4 c2[4], c1[4];
  #pragma unroll
  for (int t = 0; t < 4; t++){ c2[t] = (floatx4){0,0,0,0}; c1[t] = (floatx4){0,0,0,0}; }
  #pragma unroll
  for (int tk = 0; tk < 4; tk++){
    short8 a = *(const short8*)&tileM[ln][tk*32 + q*8];
    #pragma unroll
    for (int t = 0; t < 4; t++){
      const int tn_g = wv*4 + t;
      short8 b2 = *(const short8*)(w21sw + (size_t)((tk*8 + tn_g)*64 + lane)*8);
      c2[t] = __builtin_amdgcn_mfma_f32_16x16x32_bf16(a, b2, c2[t], 0, 0, 0);
      short8 b1 = *(const short8*)(w11sw + (size_t)((tk*8 + tn_g)*64 + lane)*8);
      c1[t] = __builtin_amdgcn_mfma_f32_16x16x32_bf16(a, b1, c1[t], 0, 0, 0);
    }
  }
  #pragma unroll
  for (int t = 0; t < 4; t++){
    const int n = (wv*4 + t)*16 + ln;
    #pragma unroll
    for (int r = 0; r < 4; r++){
      tileFu[(q*4 + r)*TPS + n] = f2b(fast_silu(c1[t][r]));   // t1 staging
      c2[t][r] = fast_silu(c2[t][r]);
    }
  }

  __syncthreads();   // B2: t1 complete (and all msg reads done)

  // P3: g1 = t1 @ w12; then t2 -> tileM (msg dead after B2)
  floatx4 g1[4];
  #pragma unroll
  for (int t = 0; t < 4; t++) g1[t] = (floatx4){0,0,0,0};
  #pragma unroll
  for (int tk = 0; tk < 4; tk++){
    short8 a = *(const short8*)&tileFu[(size_t)ln*TPS + tk*32 + q*8];
    #pragma unroll
    for (int t = 0; t < 4; t++){
      short8 b = *(const short8*)(w12sw + (size_t)((tk*8 + wv*4 + t)*64 + lane)*8);
      g1[t] = __builtin_amdgcn_mfma_f32_16x16x32_bf16(a, b, g1[t], 0, 0, 0);
    }
  }
  #pragma unroll
  for (int t = 0; t < 4; t++){
    const int n = (wv*4 + t)*16 + ln;
    #pragma unroll
    for (int r = 0; r < 4; r++) tileM[q*4 + r][n] = f2b(c2[t][r]);   // t2
  }

  __syncthreads();   // B3: t2 complete (and all t1 reads done)

  // P4: g2 = t2 @ w22
  floatx4 g2[4];
  #pragma unroll
  for (int t = 0; t < 4; t++) g2[t] = (floatx4){0,0,0,0};
  #pragma unroll
  for (int tk = 0; tk < 4; tk++){
    short8 a = *(const short8*)&tileM[ln][tk*32 + q*8];
    #pragma unroll
    for (int t = 0; t < 4; t++){
      short8 b = *(const short8*)(w22sw + (size_t)((tk*8 + wv*4 + t)*64 + lane)*8);
      g2[t] = __builtin_amdgcn_mfma_f32_16x16x32_bf16(a, b, g2[t], 0, 0, 0);
    }
  }

  // three d-passes (fjw per-d): tileF (own cols) <- g1*dir + g2*force_old[j];
  // flush -> force
  for (int d = 0; d < 3; d++){
    u32 fjw[4][4];
    #pragma unroll
    for (int r = 0; r < 4; r++)
      #pragma unroll
      for (int t = 0; t < 4; t++)
        fjw[r][t] = forceb[((size_t)jjR[r]*3 + d)*64 + t*16 + ln];
    #pragma unroll
    for (int t = 0; t < 4; t++){
      const int n = (wv*4 + t)*16 + ln;
      #pragma unroll
      for (int r = 0; r < 4; r++){
        float fj = wv ? hi_bf(fjw[r][t]) : lo_bf(fjw[r][t]);
        tileF[q*4 + r][n] = g1[t][r]*dirR[r][d] + g2[t][r]*fj;
      }
    }
    SEGFLUSH(&force[((size_t)ii_*3 + d)*NF])
  }
}

// ---------------- fused node kernel (4-wave tn-split, 3-d batched staging) ----------------
// Wave w owns tn {2w, 2w+1} (columns [w*32, w*32+32)). 256 threads stage 24
// elements each (two coalesced row-groups: thread covers column tid&127,
// row-half tid>>7). Packed u16 mapping for forceb/hb generalizes as
// word = col&63, half = col>>6 (bit-identical to packbf layout).
__global__ __launch_bounds__(256, 2) void k_node(
    const float* __restrict__ force,
    const u16* __restrict__ eusw, u32* __restrict__ forceb,
    float* __restrict__ atom,
    const u16* __restrict__ w1sw, const float* __restrict__ b1,
    const u16* __restrict__ w2sw, const float* __restrict__ b2,
    u32* __restrict__ hb, int do_mlp)
{
  __shared__ __align__(16) u16 tileM3[3][16][TPS];
  __shared__ __align__(16) float tileF3[3][16][TPF];
  const int w = threadIdx.x >> 6;           // 0..3
  const int lane = threadIdx.x & 63;
  const int q = lane >> 4, ln = lane & 15;
  const int n0 = blockIdx.x * 16;
  const int cc2 = threadIdx.x & 127;        // staging column
  const int mh  = (threadIdx.x >> 7) * 8;   // staging row-half base

  // stage all 3 d upfront: 24 coalesced loads/thread in one pipelined burst
  #pragma unroll
  for (int d = 0; d < 3; d++)
    #pragma unroll
    for (int m8 = 0; m8 < 8; m8++){
      int m = mh + m8;
      size_t idx = ((size_t)(n0+m)*3 + d)*NF + cc2;
      float v = force[idx];
      if (do_mlp)
        ((u16*)forceb)[(((size_t)(n0+m)*3 + d)*64 + (cc2 & 63))*2 + (cc2 >> 6)] = f2b(v);
      tileM3[d][m][cc2] = f2b(v);
      tileF3[d][m][cc2] = v;
    }
  __syncthreads();   // all tiles staged

  float acc[2][4];
  #pragma unroll
  for (int t = 0; t < 2; t++)
    #pragma unroll
    for (int r = 0; r < 4; r++) acc[t][r] = 0.f;

  #pragma unroll
  for (int d = 0; d < 3; d++){
    floatx4 c[2];
    #pragma unroll
    for (int t = 0; t < 2; t++) c[t] = (floatx4){0,0,0,0};
    #pragma unroll
    for (int tk = 0; tk < 4; tk++){
      short8 a = *(const short8*)&tileM3[d][ln][tk*32 + q*8];
      #pragma unroll
      for (int t = 0; t < 2; t++){
        short8 b = *(const short8*)(eusw + (size_t)((tk*8 + w*2 + t)*64 + lane)*8);
        c[t] = __builtin_amdgcn_mfma_f32_16x16x32_bf16(a, b, c[t], 0, 0, 0);
      }
    }
    #pragma unroll
    for (int t = 0; t < 2; t++){
      int n = (w*2 + t)*16 + ln;
      #pragma unroll
      for (int r = 0; r < 4; r++)
        acc[t][r] += tileF3[d][q*4 + r][n] * c[t][r];
    }
  }

  float anew[2][4];
  #pragma unroll
  for (int t = 0; t < 2; t++){
    int n = (w*2 + t)*16 + ln;
    #pragma unroll
    for (int r = 0; r < 4; r++){
      size_t idx = (size_t)(n0 + q*4 + r)*NF + n;
      float v = atom[idx] + acc[t][r];
      atom[idx] = v;
      anew[t][r] = v;
    }
  }
  if (!do_mlp) return;

  u16 (*tile)[TPS] = tileM3[0];
  __syncthreads();   // eu A-reads of tileM3[0] (all waves) done before overwrite
  #pragma unroll
  for (int t = 0; t < 2; t++){
    int n = (w*2 + t)*16 + ln;
    #pragma unroll
    for (int r = 0; r < 4; r++) tile[q*4 + r][n] = f2b(anew[t][r]);
  }
  __syncthreads();   // anew staged
  floatx4 c1[2];
  #pragma unroll
  for (int t = 0; t < 2; t++) c1[t] = (floatx4){0,0,0,0};
  #pragma unroll
  for (int tk = 0; tk < 4; tk++){
    short8 a = *(const short8*)&tile[ln][tk*32 + q*8];
    #pragma unroll
    for (int t = 0; t < 2; t++){
      short8 b = *(const short8*)(w1sw + (size_t)((tk*8 + w*2 + t)*64 + lane)*8);
      c1[t] = __builtin_amdgcn_mfma_f32_16x16x32_bf16(a, b, c1[t], 0, 0, 0);
    }
  }
  __syncthreads();   // c1 A-reads done before silu overwrite
  #pragma unroll
  for (int t = 0; t < 2; t++){
    int n = (w*2 + t)*16 + ln;
    float bias = b1[n];
    #pragma unroll
    for (int r = 0; r < 4; r++)
      tile[q*4 + r][n] = f2b(fast_silu(c1[t][r] + bias));
  }
  __syncthreads();   // t1 staged
  floatx4 c2[2];
  #pragma unroll
  for (int t = 0; t < 2; t++) c2[t] = (floatx4){0,0,0,0};
  #pragma unroll
  for (int tk = 0; tk < 4; tk++){
    short8 a = *(const short8*)&tile[ln][tk*32 + q*8];
    #pragma unroll
    for (int t = 0; t < 2; t++){
      short8 b = *(const short8*)(w2sw + (size_t)((tk*8 + w*2 + t)*64 + lane)*8);
      c2[t] = __builtin_amdgcn_mfma_f32_16x16x32_bf16(a, b, c2[t], 0, 0, 0);
    }
  }
  #pragma unroll
  for (int t = 0; t < 2; t++){
    int tn = w*2 + t;
    float bias = b2[tn*16 + ln];
    #pragma unroll
    for (int r = 0; r < 4; r++)
      ((u16*)hb)[(((size_t)(n0 + q*4 + r))*64 + (tn & 3)*16 + ln)*2 + (tn >> 2)] = f2b(c2[t][r] + bias);
  }
}

// ---------------- write out ----------------
__global__ __launch_bounds__(256) void k_writeout(const float* __restrict__ atom,
                                                  const float* __restrict__ force,
                                                  void* __restrict__ out,
                                                  const int* __restrict__ flag){
  int idx = blockIdx.x * 256 + threadIdx.x;
  const int na = NN * NF;
  const int tot = na + NN * 3 * NF;
  if (idx >= tot) return;
  float v = (idx < na) ? atom[idx] : force[idx - na];
  if (*flag) ((__hip_bfloat16*)out)[idx] = __float2bfloat16(v);
  else       ((float*)out)[idx] = v;
}

extern "C" void kernel_launch(void* const* d_in, const int* in_sizes, int n_in,
                              void* d_out, int out_size, void* d_ws, size_t ws_size,
                              hipStream_t stream){
  const int* z    = (const int*)d_in[0];
  const void* pos = d_in[1];
  // d_in[2] cell, d_in[3] batch: numerically dead (sym == I)
  const int* ei   = (const int*)d_in[4];
  const void* emb   = d_in[5];
  const void* mnpW1 = d_in[6];
  const void* mnpb1 = d_in[7];
  const void* mnpW2 = d_in[8];
  const void* mnpb2 = d_in[9];
  const void* meW   = d_in[10];
  const void* em1W1 = d_in[11];
  const void* em1W2 = d_in[12];
  const void* em2W1 = d_in[13];
  const void* em2W2 = d_in[14];
  const void* euW   = d_in[15];

  float* base  = (float*)d_ws;
  int*   flag  = (int*)d_ws;                  // 4 floats reserved
  float* atom   = base + 4;                   // NN*NF
  float* force  = atom   + NN*NF;             // NN*3*NF (edge atomics accumulate here)
  u32*   forceb = (u32*)(force + (size_t)NN*3*NF);   // NN*3*64
  int*   count  = (int*)(forceb + (size_t)NN*3*64);  // NN
  float* ds    = (float*)(count + NN);        // NE
  float* dirs  = ds + NE;                     // 3*NE
  float* posf  = dirs + 3*NE;
  float* embf  = posf + NN*3;
  float* b1f   = embf + 119*NF;
  float* b2f_  = b1f + 3*NF;
  u32*   hb    = (u32*)(b2f_ + 3*NF);
  u16*   mesw  = (u16*)(hb + (size_t)NN*64);
  u16*   w11sw = mesw  + 3*4096;
  u16*   w12sw = w11sw + 3*16384;
  u16*   w21sw = w12sw + 3*16384;
  u16*   w22sw = w21sw + 3*16384;
  u16*   w1sw  = w22sw + 3*16384;
  u16*   w2sw  = w1sw  + 3*16384;
  u16*   eusw  = w2sw  + 3*16384;
  int* rowptr  = (int*)(eusw + 3*16384);
  int* cursor  = rowptr + NN + 1;
  int* iis     = cursor + NN;
  int* jjs     = iis + NE;
  u16* rbfb    = (u16*)(jjs + NE);            // NE*32 bf16 (10.24 MB)

  k_detect<<<1, 256, 0, stream>>>(meW, 3*NB*NF, flag);

  // zero force + forceb + count (contiguous)
  hipMemsetAsync(force, 0, ((size_t)NN*3*NF + (size_t)NN*3*64 + NN)*4, stream);

  PrepArgs pa;
  pa.csrc[0]=pos;   pa.cdst[0]=posf; pa.cn[0]=NN*3;
  pa.csrc[1]=emb;   pa.cdst[1]=embf; pa.cn[1]=119*NF;
  pa.csrc[2]=mnpb1; pa.cdst[2]=b1f;  pa.cn[2]=3*NF;
  pa.csrc[3]=mnpb2; pa.cdst[3]=b2f_; pa.cn[3]=3*NF;
  pa.ssrc[0]=em1W1; pa.sdst[0]=w11sw;
  pa.ssrc[1]=em1W2; pa.sdst[1]=w12sw;
  pa.ssrc[2]=em2W1; pa.sdst[2]=w21sw;
  pa.ssrc[3]=em2W2; pa.sdst[3]=w22sw;
  pa.ssrc[4]=mnpW1; pa.sdst[4]=w1sw;
  pa.ssrc[5]=mnpW2; pa.sdst[5]=w2sw;
  pa.ssrc[6]=euW;   pa.sdst[6]=eusw;
  pa.mesrc=meW;     pa.medst=mesw;
  k_prep<<<dim3(192,12), 256, 0, stream>>>(pa, flag);

  k_hist         <<<(NE+255)/256, 256, 0, stream>>>(ei, count);
  k_scan         <<<1, 256, 0, stream>>>(count, rowptr, cursor);
  k_scatter_embed<<<(NE+255)/256, 256, 0, stream>>>(ei, cursor, posf, iis, jjs, ds, dirs);
  k_rbf          <<<(NE+255)/256, 256, 0, stream>>>(ds, rbfb);

  k_mlp0<<<NN/16, 128, 0, stream>>>(z, embf, atom, w1sw, b1f, w2sw, b2f_, hb);
  for (int l = 0; l < 3; l++){
    k_edge_mfma<<<NE/16, 128, 0, stream>>>(iis, jjs, rbfb, dirs, hb,
        mesw  + (size_t)l*4096,
        w11sw + (size_t)l*16384, w12sw + (size_t)l*16384,
        w21sw + (size_t)l*16384, w22sw + (size_t)l*16384,
        atom, forceb, force);
    int nl = l + 1;
    k_node<<<NN/16, 256, 0, stream>>>(force,
        eusw + (size_t)l*16384, forceb, atom,
        w1sw + (size_t)(nl%3)*16384, b1f + (size_t)(nl%3)*NF,
        w2sw + (size_t)(nl%3)*16384, b2f_ + (size_t)(nl%3)*NF,
        hb, (l < 2) ? 1 : 0);
  }

  k_writeout<<<(NN*NF + NN*3*NF + 255)/256, 256, 0, stream>>>(atom, force, d_out, flag);
}